// Round 16
// baseline (58.868 us; speedup 1.0000x reference)
//
#include <hip/hip_runtime.h>

#define BATCH 4096
#define SEQ   80
#define EMBED 100
#define UNITS 64
#define NTILE (BATCH / 16)      // 256 batch tiles of 16 rows
#define NVOC  10000
#define NVWV  ((NVOC + 15) / 16)
#define NPAIR2 (SEQ / 2)        // 40 timestep pairs

typedef float f32x4  __attribute__((ext_vector_type(4)));
typedef short bf16x8 __attribute__((ext_vector_type(8)));

#define MFMA16 __builtin_amdgcn_mfma_f32_16x16x32_bf16

// ---- ws layout (bytes) ----
#define TAB_OFF 0u           // bf16 table[10000][64] = 1,280,000 B (L2-resident)
#define XW2_OFF 1280000u     // uint4[256*4*40*64] = 41,943,040 B (pair-packed)

__device__ __forceinline__ unsigned f2bfu(float f) {
    union { float f; unsigned u; } x; x.f = f;
    return (x.u + 0x7fffu + ((x.u >> 16) & 1u)) >> 16;   // RNE
}
__device__ __forceinline__ unsigned cvtpk(float lo, float hi) {
    unsigned r;
    asm("v_cvt_pk_bf16_f32 %0, %1, %2" : "=v"(r) : "v"(lo), "v"(hi));
    return r;
}
__device__ __forceinline__ float bflo(unsigned u) {
    union { unsigned u; float f; } x; x.u = u << 16; return x.f;
}
__device__ __forceinline__ float bfhi(unsigned u) {
    union { unsigned u; float f; } x; x.u = u & 0xffff0000u; return x.f;
}
// branch-free exact-tails tanh: 1 - 2/(e^{2x}+1)
__device__ __forceinline__ float fast_tanh(float x) {
    float e = __builtin_amdgcn_exp2f(x * 2.8853900817779268f);
    float r = __builtin_amdgcn_rcpf(e + 1.0f);
    return __builtin_fmaf(-2.0f, r, 1.0f);
}

// ---------------------------------------------------------------------------
// tableproj: table[v] = b1 + emb[v] @ W1 for all 10000 vocab rows.
// W1 A-frags built from f32 directly (same RNE rounding as before).
// ---------------------------------------------------------------------------
__global__ __launch_bounds__(256) void tableproj_kernel(
    const float* __restrict__ emb,
    const float* __restrict__ b1,
    const float* __restrict__ W1,
    char* __restrict__ table)
{
    const int lane = threadIdx.x & 63;
    const int wid  = threadIdx.x >> 6;
    const int gw   = blockIdx.x * 4 + wid;
    if (gw >= NVWV) return;
    const int m15  = lane & 15;
    const int kgrp = lane >> 4;
    const int v    = gw * 16 + m15;
    const int vc   = v < NVOC ? v : NVOC - 1;

    bf16x8 aW1[4][4];
    #pragma unroll
    for (int mt = 0; mt < 4; ++mt) {
        const int u = 16 * mt + m15;
        #pragma unroll
        for (int ks = 0; ks < 4; ++ks)
            #pragma unroll
            for (int j = 0; j < 8; ++j) {
                const int k = kgrp * 8 + j + 32 * ks;
                aW1[mt][ks][j] = (k < EMBED) ? (short)f2bfu(W1[k * UNITS + u])
                                             : (short)0;
            }
    }

    const float* rp = emb + (size_t)vc * EMBED;
    bf16x8 bf[4];
    #pragma unroll
    for (int ks = 0; ks < 3; ++ks) {
        f32x4 e0 = *(const f32x4*)(rp + kgrp * 8 + 32 * ks);
        f32x4 e1 = *(const f32x4*)(rp + kgrp * 8 + 32 * ks + 4);
        uint4 u;
        u.x = cvtpk(e0.x, e0.y); u.y = cvtpk(e0.z, e0.w);
        u.z = cvtpk(e1.x, e1.y); u.w = cvtpk(e1.z, e1.w);
        bf[ks] = *(bf16x8*)&u;
    }
    {
        uint4 u = {0u, 0u, 0u, 0u};
        if (kgrp == 0) {
            f32x4 e0 = *(const f32x4*)(rp + 96);
            u.x = cvtpk(e0.x, e0.y); u.y = cvtpk(e0.z, e0.w);
        }
        bf[3] = *(bf16x8*)&u;
    }

    f32x4 acc[4];
    #pragma unroll
    for (int mt = 0; mt < 4; ++mt)
        acc[mt] = *(const f32x4*)(b1 + 16 * mt + 4 * kgrp);
    #pragma unroll
    for (int ks = 0; ks < 4; ++ks)
        #pragma unroll
        for (int mt = 0; mt < 4; ++mt)
            acc[mt] = MFMA16(aW1[mt][ks], bf[ks], acc[mt], 0, 0, 0);

    #pragma unroll
    for (int mt = 0; mt < 4; ++mt) {
        uint2 q;
        q.x = cvtpk(acc[mt][0], acc[mt][1]);
        q.y = cvtpk(acc[mt][2], acc[mt][3]);
        *(uint2*)(table + (size_t)v * 128 + mt * 32 + kgrp * 8) = q;
    }
}

// ---------------------------------------------------------------------------
// expand v2: 2048 waves (512 blocks, ~2/CU, 8 waves/CU). Wave (tile, w, half)
// emits 20 pair-packed xw2 lines: 2 L2 table gathers + 1 coalesced 1KB store
// per iter, all iters independent -> latency pipelined away.
// ---------------------------------------------------------------------------
__global__ __launch_bounds__(256) void expand_kernel(
    const int*   __restrict__ tokens,
    const uint2* __restrict__ table,     // [10000][16] uint2
    uint4*       __restrict__ xw2)
{
    const int lane = threadIdx.x & 63;
    const int wid  = threadIdx.x >> 6;
    const int gwid = blockIdx.x * 4 + wid;   // 0..2047
    const int tile = gwid >> 3;
    const int sub  = gwid & 7;
    const int w    = sub >> 1;
    const int half = sub & 1;
    const int m15  = lane & 15;
    const int kgrp = lane >> 4;

    const int*   tokp = tokens + (size_t)(tile * 16 + m15) * SEQ;
    const uint2* tabp = table + w * 4 + kgrp;
    uint4* outp = xw2 + ((size_t)(tile * 4 + w)) * NPAIR2 * 64 + lane;
    const int pk0 = half * (NPAIR2 / 2);

    #pragma unroll 5
    for (int i = 0; i < NPAIR2 / 2; ++i) {
        const int pk = pk0 + i;
        const int tokE = tokp[2 * pk];
        const int tokO = tokp[2 * pk + 1];
        uint2 gE = tabp[(size_t)tokE * 16];
        uint2 gO = tabp[(size_t)tokO * 16];
        uint4 o; o.x = gE.x; o.y = gE.y; o.z = gO.x; o.w = gO.y;
        outp[(size_t)pk * 64] = o;
    }
}

// ---------------------------------------------------------------------------
// rnn: R15's verified lean scan (pair-packed stream); weight A-frags built
// from f32 U1/W2/U2 directly at startup (same RNE rounding).
// ---------------------------------------------------------------------------
__global__ __launch_bounds__(256, 1) void rnn_kernel(
    const uint4*  __restrict__ xw2,
    const float*  __restrict__ U1,
    const float*  __restrict__ W2,
    const float*  __restrict__ U2,
    const float*  __restrict__ b2,
    const float*  __restrict__ Wo,
    const float*  __restrict__ bo,
    float*        __restrict__ out)
{
    __shared__ __align__(16) char h1L[2][2048];   // [buf][16b x 64u bf16, swz]
    __shared__ __align__(16) char h2L[2][2048];
    __shared__ float headp[4][16];

    const int lane = threadIdx.x & 63;
    const int w    = threadIdx.x >> 6;
    const int m15  = lane & 15;
    const int kgrp = lane >> 4;
    const int swz  = (m15 & 7) << 4;
    const int wg   = blockIdx.x;

    {
        uint4 z = {0u, 0u, 0u, 0u};
        if (threadIdx.x < 128) ((uint4*)h2L[0])[threadIdx.x] = z;
    }

    const int urow = 16 * w + m15;
    bf16x8 aU1[2], aW2[2], aU2[2];
    #pragma unroll
    for (int ks = 0; ks < 2; ++ks)
        #pragma unroll
        for (int j = 0; j < 8; ++j) {
            const int k = kgrp * 8 + j + 32 * ks;
            aU1[ks][j] = (short)f2bfu(U1[k * UNITS + urow]);
            aW2[ks][j] = (short)f2bfu(W2[k * UNITS + urow]);
            aU2[ks][j] = (short)f2bfu(U2[k * UNITS + urow]);
        }
    const int ubase = 16 * w + 4 * kgrp;
    const f32x4 b2c = *(const f32x4*)(b2 + ubase);

    // pair-packed stream: pair pk at xwp[pk*64]; holds {xw[2pk], xw[2pk+1]}
    const uint4* xwp = xw2 + ((size_t)(wg * 4 + w)) * NPAIR2 * 64 + lane;
    uint4 r0 = xwp[0];
    uint4 r1 = xwp[64];
    uint4 r2 = xwp[2 * 64];

    // prologue: h1[0] = tanh(xw[0]) -> buf 0   (xw[0] = r0.xy)
    {
        float t0 = fast_tanh(bflo(r0.x)), t1 = fast_tanh(bfhi(r0.x));
        float t2 = fast_tanh(bflo(r0.y)), t3 = fast_tanh(bfhi(r0.y));
        uint2 pk; pk.x = cvtpk(t0, t1); pk.y = cvtpk(t2, t3);
        *(uint2*)(h1L[0] + m15 * 128 + ((32 * w + 8 * kgrp) ^ swz)) = pk;
    }
    asm volatile("s_waitcnt lgkmcnt(0)" ::: "memory");
    __builtin_amdgcn_s_barrier();

    float d2f0 = 0.f, d2f1 = 0.f, d2f2 = 0.f, d2f3 = 0.f;

#define LBAR() do { asm volatile("s_waitcnt lgkmcnt(0)" ::: "memory"); \
                    __builtin_amdgcn_s_barrier(); } while (0)
// One phase; (QX,QY) = packed bf16 xw[T+1]. Math identical to R8 (verified).
#define PHASE(QX, QY, P, Q)                                                      \
  {                                                                              \
    bf16x8 bh1a = *(const bf16x8*)(h1L[P] + m15 * 128 + ((kgrp * 16     ) ^ swz)); \
    bf16x8 bh1b = *(const bf16x8*)(h1L[P] + m15 * 128 + ((kgrp * 16 + 64) ^ swz)); \
    bf16x8 bh2a = *(const bf16x8*)(h2L[P] + m15 * 128 + ((kgrp * 16     ) ^ swz)); \
    bf16x8 bh2b = *(const bf16x8*)(h2L[P] + m15 * 128 + ((kgrp * 16 + 64) ^ swz)); \
    f32x4 d1 = {bflo(QX), bfhi(QX), bflo(QY), bfhi(QY)};                         \
    d1 = MFMA16(aU1[0], bh1a, d1, 0, 0, 0);                                      \
    d1 = MFMA16(aU1[1], bh1b, d1, 0, 0, 0);                                      \
    f32x4 dC = b2c;                                                              \
    dC = MFMA16(aW2[0], bh1a, dC, 0, 0, 0);                                      \
    dC = MFMA16(aW2[1], bh1b, dC, 0, 0, 0);                                      \
    f32x4 dD = {0.f, 0.f, 0.f, 0.f};                                             \
    dD = MFMA16(aU2[0], bh2a, dD, 0, 0, 0);                                      \
    dD = MFMA16(aU2[1], bh2b, dD, 0, 0, 0);                                      \
    float n0 = fast_tanh(d1[0]);                                                 \
    float n1 = fast_tanh(d1[1]);                                                 \
    float n2 = fast_tanh(d1[2]);                                                 \
    float n3 = fast_tanh(d1[3]);                                                 \
    d2f0 = fast_tanh(dC[0] + dD[0]);                                             \
    d2f1 = fast_tanh(dC[1] + dD[1]);                                             \
    d2f2 = fast_tanh(dC[2] + dD[2]);                                             \
    d2f3 = fast_tanh(dC[3] + dD[3]);                                             \
    {                                                                            \
        uint2 pk; pk.x = cvtpk(n0, n1); pk.y = cvtpk(n2, n3);                    \
        *(uint2*)(h1L[Q] + m15 * 128 + ((32 * w + 8 * kgrp) ^ swz)) = pk;        \
    }                                                                            \
    {                                                                            \
        uint2 pk; pk.x = cvtpk(d2f0, d2f1); pk.y = cvtpk(d2f2, d2f3);            \
        *(uint2*)(h2L[Q] + m15 * 128 + ((32 * w + 8 * kgrp) ^ swz)) = pk;        \
    }                                                                            \
    LBAR();                                                                      \
  }

    for (int k = 0; k < NPAIR2; ++k) {
        const int pn = (k + 3 < NPAIR2) ? k + 3 : NPAIR2 - 1;
        uint4 r3 = xwp[(size_t)pn * 64];
        PHASE(r0.z, r0.w, 0, 1)     // phase 2k   uses xw[2k+1]
        PHASE(r1.x, r1.y, 1, 0)     // phase 2k+1 uses xw[2k+2]
        r0 = r1; r1 = r2; r2 = r3;
    }
#undef PHASE
#undef LBAR

    // ---- head: out[b] = sigmoid(h2[79] @ Wo + bo) ----
    const f32x4 woc = *(const f32x4*)(Wo + ubase);
    float p = d2f0 * woc[0] + d2f1 * woc[1] + d2f2 * woc[2] + d2f3 * woc[3];
    p += __shfl_xor(p, 16, 64);
    p += __shfl_xor(p, 32, 64);
    if (lane < 16) headp[w][lane] = p;
    __syncthreads();
    if (threadIdx.x < 16) {
        const float z = headp[0][threadIdx.x] + headp[1][threadIdx.x]
                      + headp[2][threadIdx.x] + headp[3][threadIdx.x] + bo[0];
        const float e = __builtin_amdgcn_exp2f(-z * 1.4426950408889634f);
        out[wg * 16 + threadIdx.x] = __builtin_amdgcn_rcpf(1.0f + e);
    }
}

extern "C" void kernel_launch(void* const* d_in, const int* in_sizes, int n_in,
                              void* d_out, int out_size, void* d_ws, size_t ws_size,
                              hipStream_t stream) {
    const int*   tokens = (const int*)  d_in[0];
    const float* emb    = (const float*)d_in[1];
    const float* W1     = (const float*)d_in[2];
    const float* U1     = (const float*)d_in[3];
    const float* b1     = (const float*)d_in[4];
    const float* W2     = (const float*)d_in[5];
    const float* U2     = (const float*)d_in[6];
    const float* b2     = (const float*)d_in[7];
    const float* Wo     = (const float*)d_in[8];
    const float* bo     = (const float*)d_in[9];
    float* out = (float*)d_out;
    char*  ws  = (char*)d_ws;

    tableproj_kernel<<<(NVWV + 3) / 4, 256, 0, stream>>>(
        emb, b1, W1, ws + TAB_OFF);
    expand_kernel<<<512, 256, 0, stream>>>(
        tokens, (const uint2*)(ws + TAB_OFF), (uint4*)(ws + XW2_OFF));
    rnn_kernel<<<NTILE, 256, 0, stream>>>(
        (const uint4*)(ws + XW2_OFF),
        U1, W2, U2, b2, Wo, bo, out);
}

// Round 17
// 55.636 us; speedup vs baseline: 1.0581x; 1.0581x over previous
//
#include <hip/hip_runtime.h>

#define BATCH 4096
#define SEQ   80
#define EMBED 100
#define UNITS 64
#define NTILE (BATCH / 16)      // 256 batch tiles of 16 rows
#define NVOC  10000
#define NVWV  ((NVOC + 15) / 16)
#define NPAIR2 (SEQ / 2)        // 40 timestep pairs

typedef float f32x4  __attribute__((ext_vector_type(4)));
typedef short bf16x8 __attribute__((ext_vector_type(8)));

#define MFMA16 __builtin_amdgcn_mfma_f32_16x16x32_bf16

// ---- ws layout (bytes) ----
#define TAB_OFF 0u           // bf16 table[10000][64] = 1,280,000 B (L2-resident)
#define XW2_OFF 1280000u     // uint4[256*4*40*64] = 41,943,040 B (pair-packed)

__device__ __forceinline__ unsigned f2bfu(float f) {
    union { float f; unsigned u; } x; x.f = f;
    return (x.u + 0x7fffu + ((x.u >> 16) & 1u)) >> 16;   // RNE
}
__device__ __forceinline__ unsigned cvtpk(float lo, float hi) {
    unsigned r;
    asm("v_cvt_pk_bf16_f32 %0, %1, %2" : "=v"(r) : "v"(lo), "v"(hi));
    return r;
}
__device__ __forceinline__ float bflo(unsigned u) {
    union { unsigned u; float f; } x; x.u = u << 16; return x.f;
}
__device__ __forceinline__ float bfhi(unsigned u) {
    union { unsigned u; float f; } x; x.u = u & 0xffff0000u; return x.f;
}
// branch-free exact-tails tanh: 1 - 2/(e^{2x}+1)
__device__ __forceinline__ float fast_tanh(float x) {
    float e = __builtin_amdgcn_exp2f(x * 2.8853900817779268f);
    float r = __builtin_amdgcn_rcpf(e + 1.0f);
    return __builtin_fmaf(-2.0f, r, 1.0f);
}

// ---------------------------------------------------------------------------
// tableproj: table[v] = b1 + emb[v] @ W1 for all 10000 vocab rows (verified).
// ---------------------------------------------------------------------------
__global__ __launch_bounds__(256) void tableproj_kernel(
    const float* __restrict__ emb,
    const float* __restrict__ b1,
    const float* __restrict__ W1,
    char* __restrict__ table)
{
    const int lane = threadIdx.x & 63;
    const int wid  = threadIdx.x >> 6;
    const int gw   = blockIdx.x * 4 + wid;
    if (gw >= NVWV) return;
    const int m15  = lane & 15;
    const int kgrp = lane >> 4;
    const int v    = gw * 16 + m15;
    const int vc   = v < NVOC ? v : NVOC - 1;

    bf16x8 aW1[4][4];
    #pragma unroll
    for (int mt = 0; mt < 4; ++mt) {
        const int u = 16 * mt + m15;
        #pragma unroll
        for (int ks = 0; ks < 4; ++ks)
            #pragma unroll
            for (int j = 0; j < 8; ++j) {
                const int k = kgrp * 8 + j + 32 * ks;
                aW1[mt][ks][j] = (k < EMBED) ? (short)f2bfu(W1[k * UNITS + u])
                                             : (short)0;
            }
    }

    const float* rp = emb + (size_t)vc * EMBED;
    bf16x8 bf[4];
    #pragma unroll
    for (int ks = 0; ks < 3; ++ks) {
        f32x4 e0 = *(const f32x4*)(rp + kgrp * 8 + 32 * ks);
        f32x4 e1 = *(const f32x4*)(rp + kgrp * 8 + 32 * ks + 4);
        uint4 u;
        u.x = cvtpk(e0.x, e0.y); u.y = cvtpk(e0.z, e0.w);
        u.z = cvtpk(e1.x, e1.y); u.w = cvtpk(e1.z, e1.w);
        bf[ks] = *(bf16x8*)&u;
    }
    {
        uint4 u = {0u, 0u, 0u, 0u};
        if (kgrp == 0) {
            f32x4 e0 = *(const f32x4*)(rp + 96);
            u.x = cvtpk(e0.x, e0.y); u.y = cvtpk(e0.z, e0.w);
        }
        bf[3] = *(bf16x8*)&u;
    }

    f32x4 acc[4];
    #pragma unroll
    for (int mt = 0; mt < 4; ++mt)
        acc[mt] = *(const f32x4*)(b1 + 16 * mt + 4 * kgrp);
    #pragma unroll
    for (int ks = 0; ks < 4; ++ks)
        #pragma unroll
        for (int mt = 0; mt < 4; ++mt)
            acc[mt] = MFMA16(aW1[mt][ks], bf[ks], acc[mt], 0, 0, 0);

    #pragma unroll
    for (int mt = 0; mt < 4; ++mt) {
        uint2 q;
        q.x = cvtpk(acc[mt][0], acc[mt][1]);
        q.y = cvtpk(acc[mt][2], acc[mt][3]);
        *(uint2*)(table + (size_t)v * 128 + mt * 32 + kgrp * 8) = q;
    }
}

// ---------------------------------------------------------------------------
// rnn_fused: per-block expand prologue + R16's verified lean scan.
// Block = tile. Prologue: tokens -> LDS, then 40 independent
// {2 ds_read + 2 L2 gathers + 1 global store} iterations; pk 0-2 kept in
// registers, pk>=3 stored and read back L2-hot 6 phases later.
// ---------------------------------------------------------------------------
__global__ __launch_bounds__(256, 1) void rnn_kernel(
    const int*    __restrict__ tokens,
    const uint2*  __restrict__ table,    // [10000][16] uint2
    uint4*        __restrict__ xw2,
    const float*  __restrict__ U1,
    const float*  __restrict__ W2,
    const float*  __restrict__ U2,
    const float*  __restrict__ b2,
    const float*  __restrict__ Wo,
    const float*  __restrict__ bo,
    float*        __restrict__ out)
{
    __shared__ __align__(16) char h1L[2][2048];   // [buf][16b x 64u bf16, swz]
    __shared__ __align__(16) char h2L[2][2048];
    __shared__ int   tokL[16][84];                // pad 84: conflict-free
    __shared__ float headp[4][16];

    const int lane = threadIdx.x & 63;
    const int w    = threadIdx.x >> 6;
    const int m15  = lane & 15;
    const int kgrp = lane >> 4;
    const int swz  = (m15 & 7) << 4;
    const int wg   = blockIdx.x;

    // zero h2[-1] (buf 0) + cooperative token preload
    {
        uint4 z = {0u, 0u, 0u, 0u};
        if (threadIdx.x < 128) ((uint4*)h2L[0])[threadIdx.x] = z;
    }
    for (int i = threadIdx.x; i < 16 * SEQ; i += 256) {
        const int r = i / SEQ;
        const int t = i - r * SEQ;
        tokL[r][t] = tokens[(size_t)(wg * 16 + r) * SEQ + t];
    }

    // weight A-frags from f32 (issue early; latency hides under expand)
    const int urow = 16 * w + m15;
    bf16x8 aU1[2], aW2[2], aU2[2];
    #pragma unroll
    for (int ks = 0; ks < 2; ++ks)
        #pragma unroll
        for (int j = 0; j < 8; ++j) {
            const int k = kgrp * 8 + j + 32 * ks;
            aU1[ks][j] = (short)f2bfu(U1[k * UNITS + urow]);
            aW2[ks][j] = (short)f2bfu(W2[k * UNITS + urow]);
            aU2[ks][j] = (short)f2bfu(U2[k * UNITS + urow]);
        }
    const int ubase = 16 * w + 4 * kgrp;
    const f32x4 b2c = *(const f32x4*)(b2 + ubase);

    __syncthreads();   // tokL ready

    // ---- expand prologue: own slice's 40 pair-packed lines ----
    const uint2* tabp = table + w * 4 + kgrp;
    uint4* outp = xw2 + ((size_t)(wg * 4 + w)) * NPAIR2 * 64 + lane;
    uint4 r0, r1, r2;
    #pragma unroll 8
    for (int pk = 0; pk < NPAIR2; ++pk) {
        const int tokE = tokL[m15][2 * pk];
        const int tokO = tokL[m15][2 * pk + 1];
        uint2 gE = tabp[(size_t)tokE * 16];
        uint2 gO = tabp[(size_t)tokO * 16];
        uint4 o; o.x = gE.x; o.y = gE.y; o.z = gO.x; o.w = gO.y;
        if (pk == 0)      r0 = o;
        else if (pk == 1) r1 = o;
        else if (pk == 2) r2 = o;
        else              outp[(size_t)pk * 64] = o;
    }
    // drain stores before the scan's read-back path starts
    asm volatile("s_waitcnt vmcnt(0)" ::: "memory");

    // prologue: h1[0] = tanh(xw[0]) -> buf 0   (xw[0] = r0.xy)
    {
        float t0 = fast_tanh(bflo(r0.x)), t1 = fast_tanh(bfhi(r0.x));
        float t2 = fast_tanh(bflo(r0.y)), t3 = fast_tanh(bfhi(r0.y));
        uint2 pk; pk.x = cvtpk(t0, t1); pk.y = cvtpk(t2, t3);
        *(uint2*)(h1L[0] + m15 * 128 + ((32 * w + 8 * kgrp) ^ swz)) = pk;
    }
    asm volatile("s_waitcnt lgkmcnt(0)" ::: "memory");
    __builtin_amdgcn_s_barrier();

    float d2f0 = 0.f, d2f1 = 0.f, d2f2 = 0.f, d2f3 = 0.f;

#define LBAR() do { asm volatile("s_waitcnt lgkmcnt(0)" ::: "memory"); \
                    __builtin_amdgcn_s_barrier(); } while (0)
// One phase; (QX,QY) = packed bf16 xw[T+1]. Math identical to R8 (verified).
#define PHASE(QX, QY, P, Q)                                                      \
  {                                                                              \
    bf16x8 bh1a = *(const bf16x8*)(h1L[P] + m15 * 128 + ((kgrp * 16     ) ^ swz)); \
    bf16x8 bh1b = *(const bf16x8*)(h1L[P] + m15 * 128 + ((kgrp * 16 + 64) ^ swz)); \
    bf16x8 bh2a = *(const bf16x8*)(h2L[P] + m15 * 128 + ((kgrp * 16     ) ^ swz)); \
    bf16x8 bh2b = *(const bf16x8*)(h2L[P] + m15 * 128 + ((kgrp * 16 + 64) ^ swz)); \
    f32x4 d1 = {bflo(QX), bfhi(QX), bflo(QY), bfhi(QY)};                         \
    d1 = MFMA16(aU1[0], bh1a, d1, 0, 0, 0);                                      \
    d1 = MFMA16(aU1[1], bh1b, d1, 0, 0, 0);                                      \
    f32x4 dC = b2c;                                                              \
    dC = MFMA16(aW2[0], bh1a, dC, 0, 0, 0);                                      \
    dC = MFMA16(aW2[1], bh1b, dC, 0, 0, 0);                                      \
    f32x4 dD = {0.f, 0.f, 0.f, 0.f};                                             \
    dD = MFMA16(aU2[0], bh2a, dD, 0, 0, 0);                                      \
    dD = MFMA16(aU2[1], bh2b, dD, 0, 0, 0);                                      \
    float n0 = fast_tanh(d1[0]);                                                 \
    float n1 = fast_tanh(d1[1]);                                                 \
    float n2 = fast_tanh(d1[2]);                                                 \
    float n3 = fast_tanh(d1[3]);                                                 \
    d2f0 = fast_tanh(dC[0] + dD[0]);                                             \
    d2f1 = fast_tanh(dC[1] + dD[1]);                                             \
    d2f2 = fast_tanh(dC[2] + dD[2]);                                             \
    d2f3 = fast_tanh(dC[3] + dD[3]);                                             \
    {                                                                            \
        uint2 pk; pk.x = cvtpk(n0, n1); pk.y = cvtpk(n2, n3);                    \
        *(uint2*)(h1L[Q] + m15 * 128 + ((32 * w + 8 * kgrp) ^ swz)) = pk;        \
    }                                                                            \
    {                                                                            \
        uint2 pk; pk.x = cvtpk(d2f0, d2f1); pk.y = cvtpk(d2f2, d2f3);            \
        *(uint2*)(h2L[Q] + m15 * 128 + ((32 * w + 8 * kgrp) ^ swz)) = pk;        \
    }                                                                            \
    LBAR();                                                                      \
  }

    const uint4* xwp = (const uint4*)outp;
    for (int k = 0; k < NPAIR2; ++k) {
        const int pn = (k + 3 < NPAIR2) ? k + 3 : NPAIR2 - 1;
        uint4 r3 = xwp[(size_t)pn * 64];
        PHASE(r0.z, r0.w, 0, 1)     // phase 2k   uses xw[2k+1]
        PHASE(r1.x, r1.y, 1, 0)     // phase 2k+1 uses xw[2k+2]
        r0 = r1; r1 = r2; r2 = r3;
    }
#undef PHASE
#undef LBAR

    // ---- head: out[b] = sigmoid(h2[79] @ Wo + bo) ----
    const f32x4 woc = *(const f32x4*)(Wo + ubase);
    float p = d2f0 * woc[0] + d2f1 * woc[1] + d2f2 * woc[2] + d2f3 * woc[3];
    p += __shfl_xor(p, 16, 64);
    p += __shfl_xor(p, 32, 64);
    if (lane < 16) headp[w][lane] = p;
    __syncthreads();
    if (threadIdx.x < 16) {
        const float z = headp[0][threadIdx.x] + headp[1][threadIdx.x]
                      + headp[2][threadIdx.x] + headp[3][threadIdx.x] + bo[0];
        const float e = __builtin_amdgcn_exp2f(-z * 1.4426950408889634f);
        out[wg * 16 + threadIdx.x] = __builtin_amdgcn_rcpf(1.0f + e);
    }
}

extern "C" void kernel_launch(void* const* d_in, const int* in_sizes, int n_in,
                              void* d_out, int out_size, void* d_ws, size_t ws_size,
                              hipStream_t stream) {
    const int*   tokens = (const int*)  d_in[0];
    const float* emb    = (const float*)d_in[1];
    const float* W1     = (const float*)d_in[2];
    const float* U1     = (const float*)d_in[3];
    const float* b1     = (const float*)d_in[4];
    const float* W2     = (const float*)d_in[5];
    const float* U2     = (const float*)d_in[6];
    const float* b2     = (const float*)d_in[7];
    const float* Wo     = (const float*)d_in[8];
    const float* bo     = (const float*)d_in[9];
    float* out = (float*)d_out;
    char*  ws  = (char*)d_ws;

    tableproj_kernel<<<(NVWV + 3) / 4, 256, 0, stream>>>(
        emb, b1, W1, ws + TAB_OFF);
    rnn_kernel<<<NTILE, 256, 0, stream>>>(
        tokens, (const uint2*)(ws + TAB_OFF), (uint4*)(ws + XW2_OFF),
        U1, W2, U2, b2, Wo, bo, out);
}

// Round 18
// 45.543 us; speedup vs baseline: 1.2926x; 1.2216x over previous
//
#include <hip/hip_runtime.h>

#define BATCH 4096
#define SEQ   80
#define EMBED 100
#define UNITS 64
#define NTILE (BATCH / 16)      // 256 batch tiles of 16 rows
#define NVOC  10000
#define NVWV  ((NVOC + 15) / 16)
#define NPAIR2 (SEQ / 2)

typedef float f32x4  __attribute__((ext_vector_type(4)));
typedef short bf16x8 __attribute__((ext_vector_type(8)));

#define MFMA16 __builtin_amdgcn_mfma_f32_16x16x32_bf16

// ---- ws layout (bytes) ----
#define TAB_OFF 0u           // bf16 table[10000][64] = 1,280,000 B (L2-resident)

__device__ __forceinline__ unsigned f2bfu(float f) {
    union { float f; unsigned u; } x; x.f = f;
    return (x.u + 0x7fffu + ((x.u >> 16) & 1u)) >> 16;   // RNE
}
__device__ __forceinline__ unsigned cvtpk(float lo, float hi) {
    unsigned r;
    asm("v_cvt_pk_bf16_f32 %0, %1, %2" : "=v"(r) : "v"(lo), "v"(hi));
    return r;
}
__device__ __forceinline__ float bflo(unsigned u) {
    union { unsigned u; float f; } x; x.u = u << 16; return x.f;
}
__device__ __forceinline__ float bfhi(unsigned u) {
    union { unsigned u; float f; } x; x.u = u & 0xffff0000u; return x.f;
}
// branch-free exact-tails tanh: 1 - 2/(e^{2x}+1)
__device__ __forceinline__ float fast_tanh(float x) {
    float e = __builtin_amdgcn_exp2f(x * 2.8853900817779268f);
    float r = __builtin_amdgcn_rcpf(e + 1.0f);
    return __builtin_fmaf(-2.0f, r, 1.0f);
}

// ---------------------------------------------------------------------------
// tableproj: table[v] = b1 + emb[v] @ W1 for all 10000 vocab rows (verified).
// ---------------------------------------------------------------------------
__global__ __launch_bounds__(256) void tableproj_kernel(
    const float* __restrict__ emb,
    const float* __restrict__ b1,
    const float* __restrict__ W1,
    char* __restrict__ table)
{
    const int lane = threadIdx.x & 63;
    const int wid  = threadIdx.x >> 6;
    const int gw   = blockIdx.x * 4 + wid;
    if (gw >= NVWV) return;
    const int m15  = lane & 15;
    const int kgrp = lane >> 4;
    const int v    = gw * 16 + m15;
    const int vc   = v < NVOC ? v : NVOC - 1;

    bf16x8 aW1[4][4];
    #pragma unroll
    for (int mt = 0; mt < 4; ++mt) {
        const int u = 16 * mt + m15;
        #pragma unroll
        for (int ks = 0; ks < 4; ++ks)
            #pragma unroll
            for (int j = 0; j < 8; ++j) {
                const int k = kgrp * 8 + j + 32 * ks;
                aW1[mt][ks][j] = (k < EMBED) ? (short)f2bfu(W1[k * UNITS + u])
                                             : (short)0;
            }
    }

    const float* rp = emb + (size_t)vc * EMBED;
    bf16x8 bf[4];
    #pragma unroll
    for (int ks = 0; ks < 3; ++ks) {
        f32x4 e0 = *(const f32x4*)(rp + kgrp * 8 + 32 * ks);
        f32x4 e1 = *(const f32x4*)(rp + kgrp * 8 + 32 * ks + 4);
        uint4 u;
        u.x = cvtpk(e0.x, e0.y); u.y = cvtpk(e0.z, e0.w);
        u.z = cvtpk(e1.x, e1.y); u.w = cvtpk(e1.z, e1.w);
        bf[ks] = *(bf16x8*)&u;
    }
    {
        uint4 u = {0u, 0u, 0u, 0u};
        if (kgrp == 0) {
            f32x4 e0 = *(const f32x4*)(rp + 96);
            u.x = cvtpk(e0.x, e0.y); u.y = cvtpk(e0.z, e0.w);
        }
        bf[3] = *(bf16x8*)&u;
    }

    f32x4 acc[4];
    #pragma unroll
    for (int mt = 0; mt < 4; ++mt)
        acc[mt] = *(const f32x4*)(b1 + 16 * mt + 4 * kgrp);
    #pragma unroll
    for (int ks = 0; ks < 4; ++ks)
        #pragma unroll
        for (int mt = 0; mt < 4; ++mt)
            acc[mt] = MFMA16(aW1[mt][ks], bf[ks], acc[mt], 0, 0, 0);

    #pragma unroll
    for (int mt = 0; mt < 4; ++mt) {
        uint2 q;
        q.x = cvtpk(acc[mt][0], acc[mt][1]);
        q.y = cvtpk(acc[mt][2], acc[mt][3]);
        *(uint2*)(table + (size_t)v * 128 + mt * 32 + kgrp * 8) = q;
    }
}

// ---------------------------------------------------------------------------
// rnn: register-feed scan. Prologue gathers ALL 80 per-phase xw fragments
// into xr[80] (160 VGPR, 1 wave/SIMD so budget is 512). Loads return in
// issue order and are consumed in t-order -> late gathers overlap early
// phases via the compiler's per-use waitcnt. Scan body = verified R17 PHASE.
// ---------------------------------------------------------------------------
__global__ __launch_bounds__(256, 1) void rnn_kernel(
    const int*    __restrict__ tokens,
    const uint2*  __restrict__ table,    // [10000][16] uint2
    const float*  __restrict__ U1,
    const float*  __restrict__ W2,
    const float*  __restrict__ U2,
    const float*  __restrict__ b2,
    const float*  __restrict__ Wo,
    const float*  __restrict__ bo,
    float*        __restrict__ out)
{
    __shared__ __align__(16) char h1L[2][2048];   // [buf][16b x 64u bf16, swz]
    __shared__ __align__(16) char h2L[2][2048];
    __shared__ int   tokL[16][84];                // pad 84: conflict-free
    __shared__ float headp[4][16];

    const int lane = threadIdx.x & 63;
    const int w    = threadIdx.x >> 6;
    const int m15  = lane & 15;
    const int kgrp = lane >> 4;
    const int swz  = (m15 & 7) << 4;
    const int wg   = blockIdx.x;

    // zero h2[-1] (buf 0) + cooperative token preload
    {
        uint4 z = {0u, 0u, 0u, 0u};
        if (threadIdx.x < 128) ((uint4*)h2L[0])[threadIdx.x] = z;
    }
    for (int i = threadIdx.x; i < 16 * SEQ; i += 256) {
        const int r = i / SEQ;
        const int t = i - r * SEQ;
        tokL[r][t] = tokens[(size_t)(wg * 16 + r) * SEQ + t];
    }

    // weight A-frags from f32 (latency hidden under gather prologue)
    const int urow = 16 * w + m15;
    bf16x8 aU1[2], aW2[2], aU2[2];
    #pragma unroll
    for (int ks = 0; ks < 2; ++ks)
        #pragma unroll
        for (int j = 0; j < 8; ++j) {
            const int k = kgrp * 8 + j + 32 * ks;
            aU1[ks][j] = (short)f2bfu(U1[k * UNITS + urow]);
            aW2[ks][j] = (short)f2bfu(W2[k * UNITS + urow]);
            aU2[ks][j] = (short)f2bfu(U2[k * UNITS + urow]);
        }
    const int ubase = 16 * w + 4 * kgrp;
    const f32x4 b2c = *(const f32x4*)(b2 + ubase);

    __syncthreads();   // tokL ready

    // ---- register feed: gather all 80 xw fragments (this wave's slice) ----
    const uint2* tabp = table + w * 4 + kgrp;
    uint2 xr[SEQ];
    #pragma unroll
    for (int t = 0; t < SEQ; ++t)
        xr[t] = tabp[(size_t)tokL[m15][t] * 16];

    // prologue: h1[0] = tanh(xw[0]) -> buf 0
    {
        float t0 = fast_tanh(bflo(xr[0].x)), t1 = fast_tanh(bfhi(xr[0].x));
        float t2 = fast_tanh(bflo(xr[0].y)), t3 = fast_tanh(bfhi(xr[0].y));
        uint2 pk; pk.x = cvtpk(t0, t1); pk.y = cvtpk(t2, t3);
        *(uint2*)(h1L[0] + m15 * 128 + ((32 * w + 8 * kgrp) ^ swz)) = pk;
    }
    asm volatile("s_waitcnt lgkmcnt(0)" ::: "memory");
    __builtin_amdgcn_s_barrier();

    float d2f0 = 0.f, d2f1 = 0.f, d2f2 = 0.f, d2f3 = 0.f;

#define LBAR() do { asm volatile("s_waitcnt lgkmcnt(0)" ::: "memory"); \
                    __builtin_amdgcn_s_barrier(); } while (0)
// One phase; Q2 = packed bf16 xw[T+1] (uint2, register). Verified math.
#define PHASE(Q2, P, Q)                                                          \
  {                                                                              \
    bf16x8 bh1a = *(const bf16x8*)(h1L[P] + m15 * 128 + ((kgrp * 16     ) ^ swz)); \
    bf16x8 bh1b = *(const bf16x8*)(h1L[P] + m15 * 128 + ((kgrp * 16 + 64) ^ swz)); \
    bf16x8 bh2a = *(const bf16x8*)(h2L[P] + m15 * 128 + ((kgrp * 16     ) ^ swz)); \
    bf16x8 bh2b = *(const bf16x8*)(h2L[P] + m15 * 128 + ((kgrp * 16 + 64) ^ swz)); \
    f32x4 d1 = {bflo((Q2).x), bfhi((Q2).x), bflo((Q2).y), bfhi((Q2).y)};         \
    d1 = MFMA16(aU1[0], bh1a, d1, 0, 0, 0);                                      \
    d1 = MFMA16(aU1[1], bh1b, d1, 0, 0, 0);                                      \
    f32x4 dC = b2c;                                                              \
    dC = MFMA16(aW2[0], bh1a, dC, 0, 0, 0);                                      \
    dC = MFMA16(aW2[1], bh1b, dC, 0, 0, 0);                                      \
    f32x4 dD = {0.f, 0.f, 0.f, 0.f};                                             \
    dD = MFMA16(aU2[0], bh2a, dD, 0, 0, 0);                                      \
    dD = MFMA16(aU2[1], bh2b, dD, 0, 0, 0);                                      \
    float n0 = fast_tanh(d1[0]);                                                 \
    float n1 = fast_tanh(d1[1]);                                                 \
    float n2 = fast_tanh(d1[2]);                                                 \
    float n3 = fast_tanh(d1[3]);                                                 \
    d2f0 = fast_tanh(dC[0] + dD[0]);                                             \
    d2f1 = fast_tanh(dC[1] + dD[1]);                                             \
    d2f2 = fast_tanh(dC[2] + dD[2]);                                             \
    d2f3 = fast_tanh(dC[3] + dD[3]);                                             \
    {                                                                            \
        uint2 pk; pk.x = cvtpk(n0, n1); pk.y = cvtpk(n2, n3);                    \
        *(uint2*)(h1L[Q] + m15 * 128 + ((32 * w + 8 * kgrp) ^ swz)) = pk;        \
    }                                                                            \
    {                                                                            \
        uint2 pk; pk.x = cvtpk(d2f0, d2f1); pk.y = cvtpk(d2f2, d2f3);            \
        *(uint2*)(h2L[Q] + m15 * 128 + ((32 * w + 8 * kgrp) ^ swz)) = pk;        \
    }                                                                            \
    LBAR();                                                                      \
  }

    #pragma unroll
    for (int k = 0; k < NPAIR2; ++k) {
        PHASE(xr[2 * k + 1], 0, 1)                               // phase 2k
        PHASE(xr[(2 * k + 2 < SEQ) ? 2 * k + 2 : SEQ - 1], 1, 0) // phase 2k+1
    }
#undef PHASE
#undef LBAR

    // ---- head: out[b] = sigmoid(h2[79] @ Wo + bo) ----
    const f32x4 woc = *(const f32x4*)(Wo + ubase);
    float p = d2f0 * woc[0] + d2f1 * woc[1] + d2f2 * woc[2] + d2f3 * woc[3];
    p += __shfl_xor(p, 16, 64);
    p += __shfl_xor(p, 32, 64);
    if (lane < 16) headp[w][lane] = p;
    __syncthreads();
    if (threadIdx.x < 16) {
        const float z = headp[0][threadIdx.x] + headp[1][threadIdx.x]
                      + headp[2][threadIdx.x] + headp[3][threadIdx.x] + bo[0];
        const float e = __builtin_amdgcn_exp2f(-z * 1.4426950408889634f);
        out[wg * 16 + threadIdx.x] = __builtin_amdgcn_rcpf(1.0f + e);
    }
}

extern "C" void kernel_launch(void* const* d_in, const int* in_sizes, int n_in,
                              void* d_out, int out_size, void* d_ws, size_t ws_size,
                              hipStream_t stream) {
    const int*   tokens = (const int*)  d_in[0];
    const float* emb    = (const float*)d_in[1];
    const float* W1     = (const float*)d_in[2];
    const float* U1     = (const float*)d_in[3];
    const float* b1     = (const float*)d_in[4];
    const float* W2     = (const float*)d_in[5];
    const float* U2     = (const float*)d_in[6];
    const float* b2     = (const float*)d_in[7];
    const float* Wo     = (const float*)d_in[8];
    const float* bo     = (const float*)d_in[9];
    float* out = (float*)d_out;
    char*  ws  = (char*)d_ws;

    tableproj_kernel<<<(NVWV + 3) / 4, 256, 0, stream>>>(
        emb, b1, W1, ws + TAB_OFF);
    rnn_kernel<<<NTILE, 256, 0, stream>>>(
        tokens, (const uint2*)(ws + TAB_OFF),
        U1, W2, U2, b2, Wo, bo, out);
}